// Round 9
// baseline (4365.366 us; speedup 1.0000x reference)
//
#include <hip/hip_runtime.h>

// SentimentNet on MI355X — round 9: single sync chain per step.
//
// r8 post-mortem: readlane dot worked (7.4->4.4us/step) but the 2-group
// stagger pays the detect->dot->sync->gates chain TWICE (syncthreads
// re-couples all waves each phase). This round: ONE phase per step —
//  - each wave tag-loads all 8 batches' h (8x512B coalesced, full MLP)
//  - 8-batch readlane dot (same total VALU as r8's two phases)
//  - one syncthreads; gates distributed wave w <-> batch w (lanes 0-15)
//  - red[] parity-double-buffered (no 2nd barrier; safety: every WG
//    consumes from all 32 team WGs -> tag-wait(s) => all SYNC(s-1) =>
//    all dots(s-1) done => slot reuse at s+1 race-free)
//  - xproj layout [s][team][tb][g]: gate-lane loads fully coalesced

#define S_LEN 500
#define BATCH 64
#define EDIM 512
#define HDIM 512
#define TEAMS 8
#define WGS_PER_TEAM 32
#define TB 8
#define NBLOCKS (TEAMS * WGS_PER_TEAM)
#define NTHREADS 512

typedef unsigned long long ull;

// workspace layout (bytes)
#define XPROJ_BYTES  ((size_t)S_LEN * 2048 * BATCH * 4)   // 262,144,000
#define STATES_OFF   XPROJ_BYTES
#define STATES_BYTES ((size_t)S_LEN * BATCH * HDIM * 4)   // 65,536,000
#define HBUF_OFF     (STATES_OFF + STATES_BYTES)
#define HBUF_BYTES   ((size_t)2 * TEAMS * TB * HDIM * 8)  // 524,288 (ull)
#define PART_OFF     (HBUF_OFF + HBUF_BYTES)
#define PART_BYTES   (4 * S_LEN * BATCH * 4)              // 512,000

// ---------------- xproj GEMM: xproj[s][team][tb][g] = W_ih[g,:]·emb[idx[s,b],:] + b_ih[g]+b_hh[g]
__global__ __launch_bounds__(256) void xproj_gemm(
    const int* __restrict__ idx, const float* __restrict__ emb,
    const float* __restrict__ W_ih, const float* __restrict__ b_ih,
    const float* __restrict__ b_hh, float* __restrict__ xproj) {
  __shared__ float At[16][132];   // [k][g]
  __shared__ float Bt[16][132];   // [k][sb]
  __shared__ int sidx[128];

  const int tid = threadIdx.x;
  const int sb0 = blockIdx.x * 128;   // (s,b) flat tile
  const int g0  = blockIdx.y * 128;   // gate-row tile
  if (tid < 128) sidx[tid] = idx[sb0 + tid];

  const int ty = tid >> 4, tx = tid & 15;
  const int ra = tid & 127, pp = tid >> 7;   // row/col within tile, 8-k part

  float acc[8][8];
#pragma unroll
  for (int i = 0; i < 8; ++i)
#pragma unroll
    for (int j = 0; j < 8; ++j) acc[i][j] = 0.f;

  __syncthreads();   // sidx ready

  for (int k0 = 0; k0 < 512; k0 += 16) {
    const float* pa = &W_ih[(size_t)(g0 + ra) * 512 + k0 + 8 * pp];
    float4 a0 = *(const float4*)pa, a1 = *(const float4*)(pa + 4);
    const float* pb = &emb[(size_t)sidx[ra] * 512 + k0 + 8 * pp];
    float4 b0 = *(const float4*)pb, b1 = *(const float4*)(pb + 4);
    At[8*pp+0][ra]=a0.x; At[8*pp+1][ra]=a0.y; At[8*pp+2][ra]=a0.z; At[8*pp+3][ra]=a0.w;
    At[8*pp+4][ra]=a1.x; At[8*pp+5][ra]=a1.y; At[8*pp+6][ra]=a1.z; At[8*pp+7][ra]=a1.w;
    Bt[8*pp+0][ra]=b0.x; Bt[8*pp+1][ra]=b0.y; Bt[8*pp+2][ra]=b0.z; Bt[8*pp+3][ra]=b0.w;
    Bt[8*pp+4][ra]=b1.x; Bt[8*pp+5][ra]=b1.y; Bt[8*pp+6][ra]=b1.z; Bt[8*pp+7][ra]=b1.w;
    __syncthreads();
#pragma unroll
    for (int kk = 0; kk < 16; ++kk) {
      float4 x0 = *(const float4*)&At[kk][ty * 8];
      float4 x1 = *(const float4*)&At[kk][ty * 8 + 4];
      float4 y0 = *(const float4*)&Bt[kk][tx * 8];
      float4 y1 = *(const float4*)&Bt[kk][tx * 8 + 4];
      float av[8] = {x0.x, x0.y, x0.z, x0.w, x1.x, x1.y, x1.z, x1.w};
      float bv[8] = {y0.x, y0.y, y0.z, y0.w, y1.x, y1.y, y1.z, y1.w};
#pragma unroll
      for (int i = 0; i < 8; ++i)
#pragma unroll
        for (int j = 0; j < 8; ++j) acc[i][j] = fmaf(av[i], bv[j], acc[i][j]);
    }
    __syncthreads();
  }
  // epilogue: + bias, store g-contiguous per (s, team, tb): [s][team][tb][g]
  float biasv[8];
#pragma unroll
  for (int i = 0; i < 8; ++i)
    biasv[i] = b_ih[g0 + ty * 8 + i] + b_hh[g0 + ty * 8 + i];
  const int sbb = sb0 + tx * 8;       // 8 consecutive sb = one team's 8 tb
  const int s  = sbb >> 6;
  const int tm = (sbb & 63) >> 3;
#pragma unroll
  for (int j = 0; j < 8; ++j) {       // j = tb
    float* dst = &xproj[(((size_t)s * TEAMS + tm) * TB + j) * 2048 + g0 + ty * 8];
    float4 v0 = {acc[0][j] + biasv[0], acc[1][j] + biasv[1],
                 acc[2][j] + biasv[2], acc[3][j] + biasv[3]};
    float4 v1 = {acc[4][j] + biasv[4], acc[5][j] + biasv[5],
                 acc[6][j] + biasv[6], acc[7][j] + biasv[7]};
    *(float4*)dst = v0;
    *(float4*)(dst + 4) = v1;
  }
}

// ---------------- persistent recurrence ----------------
__global__ __launch_bounds__(NTHREADS, 1) void lstm_persistent(
    const float* __restrict__ xproj, const float* __restrict__ W_hh,
    float* __restrict__ states, ull* __restrict__ h_buf) {
  __shared__ float red[2][8][8][64];   // [par][wave][batch][lane]  32KB

  const int team = blockIdx.x & 7;           // XCD-local teams
  const int wg   = blockIdx.x >> 3;          // 0..31 -> units [16wg, 16wg+16)
  const int tid  = threadIdx.x;
  const int wv   = tid >> 6;                 // wave 0..7 -> k chunk [64wv, 64wv+64)
  const int l    = tid & 63;                 // lane

  // this lane's gate-row: g = 16wg + (l&15) + 512*(l>>4)
  const int g = 16 * wg + (l & 15) + 512 * (l >> 4);

  // register-stationary recurrent weights: lane's row, wave's 64-k chunk
  float whh[64];
  {
    const float4* phh = (const float4*)(W_hh + (size_t)g * HDIM + (size_t)wv * 64);
#pragma unroll
    for (int j = 0; j < 16; ++j) {
      float4 v = phh[j];
      whh[4*j+0] = v.x; whh[4*j+1] = v.y; whh[4*j+2] = v.z; whh[4*j+3] = v.w;
    }
  }

  // gate identity: wave wv handles batch wv, lanes 0..15 = unit gu
  const int gu = l & 15;
  const int unit = 16 * wg + gu;
  const bool gate_lane = (l < 16);
  float c_state = 0.f;

  for (int s = 0; s < S_LEN; ++s) {
    const int par = s & 1, par2 = (s + 1) & 1;

    // gate lanes prefetch this step's 4 xproj values (coalesced 64B segments)
    float xv0, xv1, xv2, xv3;
    if (gate_lane) {
      const float* p = xproj + (((size_t)s * TEAMS + team) * TB + wv) * 2048;
      xv0 = p[unit];
      xv1 = p[unit + 512];
      xv2 = p[unit + 1024];
      xv3 = p[unit + 1536];
    }

    float a0 = 0.f, a1 = 0.f, a2 = 0.f, a3 = 0.f;
    float a4 = 0.f, a5 = 0.f, a6 = 0.f, a7 = 0.f;

    if (s > 0) {
      // tagged retry-load: lane l holds h[unit 64wv+l] for all 8 team batches
      const ull* hb = h_buf + (((size_t)par * TEAMS + team) * TB) * HDIM
                      + (size_t)64 * wv + l;
      ull r0, r1, r2, r3, r4, r5, r6, r7;
      int spins = 0;
      for (;;) {
        r0 = __hip_atomic_load(hb + 0 * HDIM, __ATOMIC_RELAXED, __HIP_MEMORY_SCOPE_AGENT);
        r1 = __hip_atomic_load(hb + 1 * HDIM, __ATOMIC_RELAXED, __HIP_MEMORY_SCOPE_AGENT);
        r2 = __hip_atomic_load(hb + 2 * HDIM, __ATOMIC_RELAXED, __HIP_MEMORY_SCOPE_AGENT);
        r3 = __hip_atomic_load(hb + 3 * HDIM, __ATOMIC_RELAXED, __HIP_MEMORY_SCOPE_AGENT);
        r4 = __hip_atomic_load(hb + 4 * HDIM, __ATOMIC_RELAXED, __HIP_MEMORY_SCOPE_AGENT);
        r5 = __hip_atomic_load(hb + 5 * HDIM, __ATOMIC_RELAXED, __HIP_MEMORY_SCOPE_AGENT);
        r6 = __hip_atomic_load(hb + 6 * HDIM, __ATOMIC_RELAXED, __HIP_MEMORY_SCOPE_AGENT);
        r7 = __hip_atomic_load(hb + 7 * HDIM, __ATOMIC_RELAXED, __HIP_MEMORY_SCOPE_AGENT);
        bool ok = ((int)(r0 >> 32) == s) & ((int)(r1 >> 32) == s) &
                  ((int)(r2 >> 32) == s) & ((int)(r3 >> 32) == s) &
                  ((int)(r4 >> 32) == s) & ((int)(r5 >> 32) == s) &
                  ((int)(r6 >> 32) == s) & ((int)(r7 >> 32) == s);
        if (__all(ok)) break;
        __builtin_amdgcn_s_sleep(1);
        if (++spins > (1 << 17)) break;    // hang guard only
      }
      const int h0 = (int)(unsigned)r0, h1 = (int)(unsigned)r1;
      const int h2 = (int)(unsigned)r2, h3 = (int)(unsigned)r3;
      const int h4 = (int)(unsigned)r4, h5 = (int)(unsigned)r5;
      const int h6 = (int)(unsigned)r6, h7 = (int)(unsigned)r7;
      // 8-batch readlane dot: VALU only, no LDS
#pragma unroll
      for (int k = 0; k < 64; ++k) {
        const float wk = whh[k];
        a0 = fmaf(wk, __int_as_float(__builtin_amdgcn_readlane(h0, k)), a0);
        a1 = fmaf(wk, __int_as_float(__builtin_amdgcn_readlane(h1, k)), a1);
        a2 = fmaf(wk, __int_as_float(__builtin_amdgcn_readlane(h2, k)), a2);
        a3 = fmaf(wk, __int_as_float(__builtin_amdgcn_readlane(h3, k)), a3);
        a4 = fmaf(wk, __int_as_float(__builtin_amdgcn_readlane(h4, k)), a4);
        a5 = fmaf(wk, __int_as_float(__builtin_amdgcn_readlane(h5, k)), a5);
        a6 = fmaf(wk, __int_as_float(__builtin_amdgcn_readlane(h6, k)), a6);
        a7 = fmaf(wk, __int_as_float(__builtin_amdgcn_readlane(h7, k)), a7);
      }
    }

    // publish k-partials (stride-1 per batch row: conflict-free)
    red[par][wv][0][l] = a0;
    red[par][wv][1][l] = a1;
    red[par][wv][2][l] = a2;
    red[par][wv][3][l] = a3;
    red[par][wv][4][l] = a4;
    red[par][wv][5][l] = a5;
    red[par][wv][6][l] = a6;
    red[par][wv][7][l] = a7;
    __syncthreads();   // the ONE barrier per step

    // gates: wave wv -> batch wv, lanes 0..15 (unit gu)
    if (gate_lane) {
      float z0 = xv0, z1 = xv1, z2 = xv2, z3 = xv3;
#pragma unroll
      for (int w2 = 0; w2 < 8; ++w2) {
        z0 += red[par][w2][wv][gu +  0];
        z1 += red[par][w2][wv][gu + 16];
        z2 += red[par][w2][wv][gu + 32];
        z3 += red[par][w2][wv][gu + 48];
      }
      float i_ = 1.f / (1.f + expf(-z0));
      float f_ = 1.f / (1.f + expf(-z1));
      float g_ = tanhf(z2);
      float o_ = 1.f / (1.f + expf(-z3));
      c_state = f_ * c_state + i_ * g_;
      float h_ = o_ * tanhf(c_state);
      // single 8B fire-and-forget message (tag = s+1 | h bits)
      ull pv = ((ull)(unsigned)(s + 1) << 32) | __float_as_uint(h_);
      __hip_atomic_store(
          &h_buf[(((size_t)par2 * TEAMS + team) * TB + wv) * HDIM + unit],
          pv, __ATOMIC_RELAXED, __HIP_MEMORY_SCOPE_AGENT);
      states[((size_t)s * BATCH + team * TB + wv) * HDIM + unit] = h_;  // off-chain
    }
    // no trailing barrier: red(s+1) goes to parity^1; red(s) reuse at s+2 is
    // ordered by tag-wait(s+1) (=> all team WGs passed SYNC(s) => gates(s)
    // reads done) — all-to-all team consumption makes this transitive.
  }
}

// ---------------- attention GEMM: tanh(states@W_word + b_word) @ w_proj ----------------
#define ATP 132
__global__ __launch_bounds__(256) void attn_gemm(
    const float* __restrict__ states, const float* __restrict__ W_word,
    const float* __restrict__ b_word, const float* __restrict__ w_proj,
    float* __restrict__ part) {
  __shared__ float At[16][ATP];   // A transposed tile [k][m]
  __shared__ float Bt[16][ATP];   // B tile [k][n]
  __shared__ float redl[128][17];

  const int tid = threadIdx.x;
  const int m0 = blockIdx.x * 128;   // token tile
  const int n0 = blockIdx.y * 128;   // tanh-dim tile
  const int ty = tid >> 4, tx = tid & 15;

  float acc[8][8];
#pragma unroll
  for (int i = 0; i < 8; ++i)
#pragma unroll
    for (int j = 0; j < 8; ++j) acc[i][j] = 0.f;

  for (int k0 = 0; k0 < 512; k0 += 16) {
#pragma unroll
    for (int it = 0; it < 2; ++it) {
      int m = (tid >> 2) + 64 * it;
      int kq = tid & 3;
      float4 v = *(const float4*)&states[(size_t)(m0 + m) * 512 + k0 + 4 * kq];
      At[4 * kq + 0][m] = v.x; At[4 * kq + 1][m] = v.y;
      At[4 * kq + 2][m] = v.z; At[4 * kq + 3][m] = v.w;
    }
#pragma unroll
    for (int it = 0; it < 2; ++it) {
      int kr = (tid >> 5) + 8 * it;
      int nq = tid & 31;
      float4 v = *(const float4*)&W_word[(size_t)(k0 + kr) * 512 + n0 + 4 * nq];
      *(float4*)&Bt[kr][4 * nq] = v;
    }
    __syncthreads();
#pragma unroll
    for (int kk = 0; kk < 16; ++kk) {
      float4 a0 = *(const float4*)&At[kk][ty * 8];
      float4 a1 = *(const float4*)&At[kk][ty * 8 + 4];
      float4 b0 = *(const float4*)&Bt[kk][tx * 8];
      float4 b1 = *(const float4*)&Bt[kk][tx * 8 + 4];
      float av[8] = {a0.x, a0.y, a0.z, a0.w, a1.x, a1.y, a1.z, a1.w};
      float bv[8] = {b0.x, b0.y, b0.z, b0.w, b1.x, b1.y, b1.z, b1.w};
#pragma unroll
      for (int i = 0; i < 8; ++i)
#pragma unroll
        for (int j = 0; j < 8; ++j) acc[i][j] = fmaf(av[i], bv[j], acc[i][j]);
    }
    __syncthreads();
  }
  float bw[8], wp[8];
  {
    float4 v0 = *(const float4*)&b_word[n0 + tx * 8];
    float4 v1 = *(const float4*)&b_word[n0 + tx * 8 + 4];
    bw[0]=v0.x; bw[1]=v0.y; bw[2]=v0.z; bw[3]=v0.w; bw[4]=v1.x; bw[5]=v1.y; bw[6]=v1.z; bw[7]=v1.w;
    float4 u0 = *(const float4*)&w_proj[n0 + tx * 8];
    float4 u1 = *(const float4*)&w_proj[n0 + tx * 8 + 4];
    wp[0]=u0.x; wp[1]=u0.y; wp[2]=u0.z; wp[3]=u0.w; wp[4]=u1.x; wp[5]=u1.y; wp[6]=u1.z; wp[7]=u1.w;
  }
#pragma unroll
  for (int i = 0; i < 8; ++i) {
    float rs = 0.f;
#pragma unroll
    for (int j = 0; j < 8; ++j) rs += tanhf(acc[i][j] + bw[j]) * wp[j];
    redl[ty * 8 + i][tx] = rs;
  }
  __syncthreads();
  if (tid < 128) {
    float ssum = 0.f;
#pragma unroll
    for (int x = 0; x < 16; ++x) ssum += redl[tid][x];
    part[(size_t)blockIdx.y * (S_LEN * BATCH) + m0 + tid] = ssum;
  }
}

// ---------------- softmax over S + pooled sum + decode ----------------
__global__ __launch_bounds__(256) void softmax_pool_decode(
    const float* __restrict__ part, const float* __restrict__ states,
    const float* __restrict__ dec_W, const float* __restrict__ dec_b,
    float* __restrict__ out) {
  const int b = blockIdx.x;
  const int tid = threadIdx.x;
  __shared__ float sc[S_LEN];
  __shared__ float pool[HDIM];
  __shared__ float redm[256];

  for (int s = tid; s < S_LEN; s += 256) {
    int t = s * BATCH + b;
    sc[s] = part[t] + part[S_LEN * BATCH + t] + part[2 * S_LEN * BATCH + t] +
            part[3 * S_LEN * BATCH + t];
  }
  __syncthreads();
  float m = -1e30f;
  for (int s = tid; s < S_LEN; s += 256) m = fmaxf(m, sc[s]);
  redm[tid] = m; __syncthreads();
  for (int o = 128; o > 0; o >>= 1) {
    if (tid < o) redm[tid] = fmaxf(redm[tid], redm[tid + o]);
    __syncthreads();
  }
  const float gmax = redm[0];
  __syncthreads();
  float lsum = 0.f;
  for (int s = tid; s < S_LEN; s += 256) { float e = expf(sc[s] - gmax); sc[s] = e; lsum += e; }
  redm[tid] = lsum; __syncthreads();
  for (int o = 128; o > 0; o >>= 1) {
    if (tid < o) redm[tid] += redm[tid + o];
    __syncthreads();
  }
  const float inv = 1.f / redm[0];
  __syncthreads();
  for (int h = tid; h < HDIM; h += 256) {
    float a = 0.f;
    for (int s = 0; s < S_LEN; ++s)
      a = fmaf(sc[s], states[((size_t)s * BATCH + b) * HDIM + h], a);
    pool[h] = a * inv;
  }
  __syncthreads();
  const int lcls = tid >> 7, ch = tid & 127;
  float p = 0.f;
#pragma unroll
  for (int j = 0; j < 4; ++j)
    p = fmaf(pool[ch * 4 + j], dec_W[lcls * HDIM + ch * 4 + j], p);
  redm[tid] = p; __syncthreads();
  for (int o = 64; o > 0; o >>= 1) {
    if (ch < o) redm[tid] += redm[tid + o];
    __syncthreads();
  }
  if (ch == 0) out[b * 2 + lcls] = redm[tid] + dec_b[lcls];
}

extern "C" void kernel_launch(void* const* d_in, const int* in_sizes, int n_in,
                              void* d_out, int out_size, void* d_ws, size_t ws_size,
                              hipStream_t stream) {
  const int*   idx    = (const int*)d_in[0];
  // d_in[1] = text_lengths: unused by the reference
  const float* emb    = (const float*)d_in[2];
  const float* W_ih   = (const float*)d_in[3];
  const float* W_hh   = (const float*)d_in[4];
  const float* b_ih   = (const float*)d_in[5];
  const float* b_hh   = (const float*)d_in[6];
  const float* W_word = (const float*)d_in[7];
  const float* b_word = (const float*)d_in[8];
  const float* w_proj = (const float*)d_in[9];
  const float* dec_W  = (const float*)d_in[10];
  const float* dec_b  = (const float*)d_in[11];
  float* out = (float*)d_out;

  char* ws = (char*)d_ws;
  float* xproj  = (float*)ws;
  float* states = (float*)(ws + STATES_OFF);
  ull*   h_buf  = (ull*)(ws + HBUF_OFF);
  float* part   = (float*)(ws + PART_OFF);

  // tags must start invalid each launch (prevents cross-replay tag collision)
  hipMemsetAsync(h_buf, 0, HBUF_BYTES, stream);

  // 1) x-projection for all timesteps (parallel GEMM, 67 GFLOP)
  xproj_gemm<<<dim3(250, 16), 256, 0, stream>>>(idx, emb, W_ih, b_ih, b_hh, xproj);

  // 2) recurrence (persistent cooperative)
  void* args[] = {(void*)&xproj, (void*)&W_hh, (void*)&states, (void*)&h_buf};
  hipLaunchCooperativeKernel(lstm_persistent, dim3(NBLOCKS), dim3(NTHREADS), args, 0, stream);

  // 3) attention scores + 4) softmax/pool/decode
  attn_gemm<<<dim3(250, 4), 256, 0, stream>>>(states, W_word, b_word, w_proj, part);
  softmax_pool_decode<<<64, 256, 0, stream>>>(part, states, dec_W, dec_b, out);
}